// Round 19
// baseline (134.563 us; speedup 1.0000x reference)
//
#include <hip/hip_runtime.h>
#include <hip/hip_bf16.h>

// SpikingPolicyNet: B=8192, D_in=256, H=1024, D_out=64, T=15, TAU=20, V_TH=1
//
// Pipeline (R19: no global atomics, no memset):
//  K0 : W2 -> W2cb (bf16 W2^T + zero sentinel row; rare path only)
//  K0c: mx[j] = max_i relu(W2[i][j]) (coalesced column scan, no atomics);
//       mxb2 = max_i relu(b2_i)
//  K0d: out[b][:] = bout (unconditional broadcast; k2 overwrites flagged rows)
//  K1 : bf16-MFMA x@W1.T; epilogue folds b1, computes closed-form spike
//       interval k = ceil(log2(1-1/I)/log2(0.95)) (spikes at t=k,2k,...),
//       writes byte-plane kb[b][j], and reduces CTAB[k]*mx[j] per row into
//       LDS, then writes the block-partial to cert2d[colblock][row]
//       (distinct addresses -> no atomics; written unconditionally ->
//       deterministic, no init needed).
//  K2 : certv = sum_cb cert2d[cb][b] + 0.5367*mxb2. Soundness:
//       v2_t(no-reset) >= v2_t; I2_s <= relu(b2_i) + sum_j relu(w_ij)[k_j|s]
//       => max v2 <= 0.5367*max relu(b2) + sum_j coef(k_j)*mx[j];
//       coef(k)=0.05*max_t sum_{m:mk<=t<=15} 0.95^(t-mk) (=0.05, k>=8);
//       CTAB[k]=coef(k-1) absorbs +-1 k-flips. certv<=0.98 (typ ~0.2,
//       ~25-sigma margin) proves zero s2 spikes (absmax==0 R1-R18 incl
//       full-fp32 R1). Flagged rows (expected 0) run the R16/R17-proven
//       exact 8-bucket G-register recurrence inline.

#define B_SZ   8192
#define D_IN   256
#define H_SZ   1024
#define D_OUT  64
#define T_STEPS 15
#define CERT_THR 0.98f

typedef __attribute__((ext_vector_type(8))) short short8;
typedef __attribute__((ext_vector_type(4))) float f32x4;

__device__ __constant__ float CTAB[16] = {   // CTAB[k] = coef(k-1), k-flip robust
    0.05f,     0.53670f, 0.53670f, 0.26271f, 0.18815f, 0.12390f, 0.11863f,
    0.086755f, 0.084882f, 0.05f,   0.05f,    0.05f,    0.05f,    0.05f,
    0.05f,     0.05f};

static __device__ __forceinline__ unsigned int pk_bf16(float lo, float hi) {
    return (__builtin_bit_cast(unsigned int, hi) & 0xffff0000u) |
           (__builtin_bit_cast(unsigned int, lo) >> 16);
}
static __device__ __forceinline__ f32x4 unp4(uint2 w) {
    f32x4 r;
    r.x = __builtin_bit_cast(float, w.x << 16);
    r.y = __builtin_bit_cast(float, w.x & 0xffff0000u);
    r.z = __builtin_bit_cast(float, w.y << 16);
    r.w = __builtin_bit_cast(float, w.y & 0xffff0000u);
    return r;
}

// ---------------------------------------------------------------- K0: transpose (+ sentinel row)
__global__ __launch_bounds__(256) void k0_transpose(const float* __restrict__ W2,
                                                    unsigned short* __restrict__ W2cb) {
    __shared__ float tile[32][33];
    const int bx = blockIdx.x * 32;
    const int by = blockIdx.y * 32;
    const int tx = threadIdx.x;
    const int ty = threadIdx.y;
    #pragma unroll
    for (int i = ty; i < 32; i += 8)
        tile[i][tx] = W2[(size_t)(by + i) * H_SZ + bx + tx];
    __syncthreads();
    #pragma unroll
    for (int i = ty; i < 32; i += 8)
        W2cb[(size_t)(bx + i) * H_SZ + by + tx] =
            (unsigned short)(__builtin_bit_cast(unsigned int, tile[tx][i]) >> 16);
    if (blockIdx.x == 0 && blockIdx.y == 0) {        // zero sentinel row 1024
        const int t = ty * 32 + tx;
        #pragma unroll
        for (int i = 0; i < 4; ++i)
            W2cb[(size_t)H_SZ * H_SZ + i * 256 + t] = 0;
    }
}

// ---------------------------------------------------------------- K0c: column maxima + b2 max
__global__ __launch_bounds__(256) void k0_colmax(const float* __restrict__ W2,
                                                 const float* __restrict__ b2,
                                                 float* __restrict__ mx,
                                                 float* __restrict__ mxb2) {
    const int col = blockIdx.x * 256 + threadIdx.x;
    float m = 0.f;
    for (int i = 0; i < H_SZ; i += 4) {              // coalesced column scan
        m = fmaxf(m, W2[(size_t)(i + 0) * H_SZ + col]);
        m = fmaxf(m, W2[(size_t)(i + 1) * H_SZ + col]);
        m = fmaxf(m, W2[(size_t)(i + 2) * H_SZ + col]);
        m = fmaxf(m, W2[(size_t)(i + 3) * H_SZ + col]);
    }
    mx[col] = m;                                      // relu'd (start at 0)

    if (blockIdx.x == 0) {                            // mxb2 = max relu(b2)
        __shared__ float red[256];
        const int tid = threadIdx.x;
        float m2 = 0.f;
        #pragma unroll
        for (int i = 0; i < 4; ++i) m2 = fmaxf(m2, b2[tid + 256 * i]);
        red[tid] = m2;
        __syncthreads();
        if (tid == 0) {
            float r = 0.f;
            for (int i = 0; i < 256; ++i) r = fmaxf(r, red[i]);
            *mxb2 = r;
        }
    }
}

// ---------------------------------------------------------------- K0d: out = bout broadcast
__global__ __launch_bounds__(256) void k0_bcast(const float* __restrict__ bout,
                                                float* __restrict__ out) {
    __shared__ float4 bq[16];
    const int tid = threadIdx.x;
    if (tid < 16) bq[tid] = *(const float4*)&bout[tid * 4];
    __syncthreads();
    const int idx = blockIdx.x * 256 + tid;           // float4 index
    *(float4*)&out[(size_t)idx * 4] = bq[idx & 15];
}

// ---------------------------------------------------------------- K1: MFMA + kb + LDS cert partials
__global__ __launch_bounds__(256) void k1_mfma(const float* __restrict__ A,
                                               const float* __restrict__ Bw,
                                               const float* __restrict__ b1,
                                               const float* __restrict__ mx,
                                               unsigned char* __restrict__ kb,
                                               float* __restrict__ cert2d) {
    __shared__ unsigned int As4[2048];   // 128 rows x 32 bf16, 16B-chunk XOR swizzle
    __shared__ unsigned int Bs4[2048];
    __shared__ float certs[128];
    const int tid  = threadIdx.x;
    const int m0   = blockIdx.x * 128;
    const int n0   = blockIdx.y * 128;
    const int lane = tid & 63;
    const int wid  = tid >> 6;
    const int wr   = wid >> 1, wc = wid & 1;

    const int row0 = tid >> 2;
    const int row1 = row0 + 64;
    const int q0   = tid & 3;

    f32x4 acc[4][4] = {};
    float4 s0[8], s1[8];

    auto LOAD = [&](float4* s, int kbk) {
        const float* pa0 = A  + (m0 + row0) * D_IN + kbk + q0 * 8;
        const float* pa1 = A  + (m0 + row1) * D_IN + kbk + q0 * 8;
        const float* pb0 = Bw + (n0 + row0) * D_IN + kbk + q0 * 8;
        const float* pb1 = Bw + (n0 + row1) * D_IN + kbk + q0 * 8;
        s[0] = *(const float4*)pa0; s[1] = *(const float4*)(pa0 + 4);
        s[2] = *(const float4*)pa1; s[3] = *(const float4*)(pa1 + 4);
        s[4] = *(const float4*)pb0; s[5] = *(const float4*)(pb0 + 4);
        s[6] = *(const float4*)pb1; s[7] = *(const float4*)(pb1 + 4);
    };
    auto WRITE = [&](const float4* s) {
        const int i0 = row0 * 16 + (q0 ^ ((row0 >> 1) & 3)) * 4;
        const int i1 = row1 * 16 + (q0 ^ ((row1 >> 1) & 3)) * 4;
        *(uint4*)&As4[i0] = make_uint4(pk_bf16(s[0].x, s[0].y), pk_bf16(s[0].z, s[0].w),
                                       pk_bf16(s[1].x, s[1].y), pk_bf16(s[1].z, s[1].w));
        *(uint4*)&As4[i1] = make_uint4(pk_bf16(s[2].x, s[2].y), pk_bf16(s[2].z, s[2].w),
                                       pk_bf16(s[3].x, s[3].y), pk_bf16(s[3].z, s[3].w));
        *(uint4*)&Bs4[i0] = make_uint4(pk_bf16(s[4].x, s[4].y), pk_bf16(s[4].z, s[4].w),
                                       pk_bf16(s[5].x, s[5].y), pk_bf16(s[5].z, s[5].w));
        *(uint4*)&Bs4[i1] = make_uint4(pk_bf16(s[6].x, s[6].y), pk_bf16(s[6].z, s[6].w),
                                       pk_bf16(s[7].x, s[7].y), pk_bf16(s[7].z, s[7].w));
    };
    auto COMPUTE = [&]() {
        short8 afr[4], bfr[4];
        const int q  = lane >> 4;
        const int lr = lane & 15;
        #pragma unroll
        for (int mf = 0; mf < 4; ++mf) {
            const int ra = wr * 64 + mf * 16 + lr;
            afr[mf] = *(const short8*)&As4[ra * 16 + (q ^ ((ra >> 1) & 3)) * 4];
            const int rb = wc * 64 + mf * 16 + lr;
            bfr[mf] = *(const short8*)&Bs4[rb * 16 + (q ^ ((rb >> 1) & 3)) * 4];
        }
        #pragma unroll
        for (int mf = 0; mf < 4; ++mf)
            #pragma unroll
            for (int nf = 0; nf < 4; ++nf)
                acc[mf][nf] = __builtin_amdgcn_mfma_f32_16x16x32_bf16(
                    afr[mf], bfr[nf], acc[mf][nf], 0, 0, 0);
    };

    LOAD(s0, 0);
    for (int kk = 0; kk < D_IN; kk += 64) {
        if (kk + 32 < D_IN) LOAD(s1, kk + 32);
        __syncthreads();
        WRITE(s0);
        __syncthreads();
        COMPUTE();
        if (kk + 64 < D_IN) LOAD(s0, kk + 64);
        __syncthreads();
        WRITE(s1);
        __syncthreads();
        COMPUTE();
    }

    __syncthreads();
    if (tid < 128) certs[tid] = 0.f;
    __syncthreads();

    // Epilogue: I = acc + b1[col]; k = ceil(log2(1-1/I)*-13.5134035), 0 = none.
    const int lr = lane & 15;
    const int qq = lane >> 4;
    float b1v[4];
    #pragma unroll
    for (int nf = 0; nf < 4; ++nf) b1v[nf] = b1[n0 + wc * 64 + nf * 16 + lr];

    #pragma unroll
    for (int mf = 0; mf < 4; ++mf) {
        const int rloc = wr * 64 + mf * 16 + qq * 4;     // row - m0
        #pragma unroll
        for (int nf = 0; nf < 4; ++nf) {
            const int c = n0 + wc * 64 + nf * 16 + lr;
            const float mxc = mx[c];
            #pragma unroll
            for (int r = 0; r < 4; ++r) {
                const float I = acc[mf][nf][r] + b1v[nf];
                int k = 0;
                if (I > 1.8632055f) {
                    const float l2 = __builtin_amdgcn_logf(1.0f - __builtin_amdgcn_rcpf(I));
                    int kc = (int)__builtin_ceilf(l2 * -13.5134035f);
                    k = kc < 1 ? 1 : (kc > 15 ? 15 : kc);
                    atomicAdd(&certs[rloc + r], CTAB[k] * mxc);   // LDS atomic
                }
                kb[(size_t)(m0 + rloc + r) * H_SZ + c] = (unsigned char)k;
            }
        }
    }
    __syncthreads();
    if (tid < 128)                                        // block-private slab, no atomics
        cert2d[(size_t)blockIdx.y * B_SZ + m0 + tid] = certs[tid];
}

// ---------------------------------------------------------------- K2: cert check (+ exact fallback)
#define BQ(IDX, GV)                                                           \
    { const uint2 eq = *(const uint2*)&ent[IDX];                              \
      const unsigned sa = (unsigned)__builtin_amdgcn_readfirstlane((int)eq.x);\
      const unsigned sb = (unsigned)__builtin_amdgcn_readfirstlane((int)eq.y);\
      const uint2 qa = *(const uint2*)(W2cb + ((size_t)(sa & 0xffffu) << 10) + jc); \
      const uint2 qb = *(const uint2*)(W2cb + ((size_t)(sa >> 16) << 10) + jc);     \
      const uint2 qc = *(const uint2*)(W2cb + ((size_t)(sb & 0xffffu) << 10) + jc); \
      const uint2 qd = *(const uint2*)(W2cb + ((size_t)(sb >> 16) << 10) + jc);     \
      GV += unp4(qa); GV += unp4(qb); GV += unp4(qc); GV += unp4(qd); }

#define BLOOP(GV, R)                                                          \
    for (int i = stt[R]; i < stt[(R) + 1]; i += 4) BQ(i, GV)

__host__ __device__ constexpr unsigned divmask(int t) {   // bit k set iff k | t
    unsigned m = 0;
    for (int k = 1; k <= 15; ++k) if (t % k == 0) m |= 1u << k;
    return m;
}

#define SMALLT(T)                                                             \
    { constexpr unsigned dm = divmask(T);                                     \
      for (int i = 0; i < nsm; ++i) {                                         \
          const int ee = __builtin_amdgcn_readfirstlane((int)ent[i]);         \
          if ((dm >> (ee >> 12)) & 1) {                                       \
              const uint2 w = *(const uint2*)(W2cb + ((size_t)(ee & 0xfffu) << 10) + jc); \
              i2 += unp4(w); } } }

#define STEP                                                                  \
    { v2 = v2 * 0.95f + i2 * 0.05f;                                           \
      if (v2.x > 1.0f) { v2.x = 0.f; ++c0; }                                  \
      if (v2.y > 1.0f) { v2.y = 0.f; ++c1; }                                  \
      if (v2.z > 1.0f) { v2.z = 0.f; ++c2; }                                  \
      if (v2.w > 1.0f) { v2.w = 0.f; ++c3; } }

__global__ __launch_bounds__(256) void k2_final(const unsigned char* __restrict__ kb,
                                                const unsigned short* __restrict__ W2cb,
                                                const float* __restrict__ b2,
                                                const float* __restrict__ Wout,
                                                const float* __restrict__ bout,
                                                const float* __restrict__ cert2d,
                                                const float* __restrict__ mxb2,
                                                float* __restrict__ out) {
    const int b   = blockIdx.x;
    const int tid = threadIdx.x;
    const int jc  = tid * 4;

    float certv = 0.536708f * (*mxb2);
    #pragma unroll
    for (int cb = 0; cb < 8; ++cb) certv += cert2d[(size_t)cb * B_SZ + b];

    if (certv <= CERT_THR) return;           // ~always: out already = bout (K0d)

    // ---- exact path (R16/R17-proven): 8-bucket G-register recurrence
    __shared__ int cnt[16];
    __shared__ int curs[16];
    __shared__ int stb[9];
    __shared__ int tot;
    __shared__ __align__(8) unsigned short ent[1064];
    __shared__ float rrow[H_SZ];

    if (tid < 16) { cnt[tid] = 0; if (tid == 0) tot = 0; }
    const unsigned int kw = *(const unsigned int*)(kb + (size_t)b * H_SZ + jc);
    const f32x4 b2q = *(const f32x4*)&b2[jc];
    __syncthreads();

    if (kw) {
        #pragma unroll
        for (int u = 0; u < 4; ++u) {
            const unsigned int ku = (kw >> (8 * u)) & 0xffu;
            if (ku) atomicAdd(&cnt[(ku >= 8) ? (int)ku : 0], 1);
        }
    }
    __syncthreads();
    if (tid < 9) {
        int s = (cnt[0] + 3) & ~3;
        for (int r = 0; r < tid; ++r) s += (cnt[8 + r] + 3) & ~3;
        stb[tid] = s;
        if (tid < 8) curs[8 + tid] = s;
        if (tid == 0) curs[0] = 0;
    }
    __syncthreads();
    if (kw) {
        #pragma unroll
        for (int u = 0; u < 4; ++u) {
            const unsigned int ku = (kw >> (8 * u)) & 0xffu;
            if (ku) {
                if (ku >= 8) {
                    const int p = atomicAdd(&curs[ku], 1);
                    ent[p] = (unsigned short)(jc + u);
                } else {
                    const int p = atomicAdd(&curs[0], 1);
                    ent[p] = (unsigned short)((jc + u) | (ku << 12));
                }
            }
        }
    }
    if (tid < 8) {
        for (int p = stb[tid] + cnt[8 + tid]; p < stb[tid + 1]; ++p)
            ent[p] = (unsigned short)H_SZ;
    }
    __syncthreads();

    int stt[9];
    #pragma unroll
    for (int r = 0; r < 9; ++r) stt[r] = __builtin_amdgcn_readfirstlane(stb[r]);
    const int nsm = __builtin_amdgcn_readfirstlane(cnt[0]);

    f32x4 G8 = {0,0,0,0}, G9 = {0,0,0,0}, G10 = {0,0,0,0}, G11 = {0,0,0,0};
    f32x4 G12 = {0,0,0,0}, G13 = {0,0,0,0}, G14 = {0,0,0,0}, G15 = {0,0,0,0};
    BLOOP(G8, 0)  BLOOP(G9, 1)  BLOOP(G10, 2) BLOOP(G11, 3)
    BLOOP(G12, 4) BLOOP(G13, 5) BLOOP(G14, 6) BLOOP(G15, 7)

    f32x4 v2 = {0,0,0,0};
    int c0 = 0, c1 = 0, c2 = 0, c3 = 0;
    { f32x4 i2 = b2q;       SMALLT(1)  STEP }
    { f32x4 i2 = b2q;       SMALLT(2)  STEP }
    { f32x4 i2 = b2q;       SMALLT(3)  STEP }
    { f32x4 i2 = b2q;       SMALLT(4)  STEP }
    { f32x4 i2 = b2q;       SMALLT(5)  STEP }
    { f32x4 i2 = b2q;       SMALLT(6)  STEP }
    { f32x4 i2 = b2q;       SMALLT(7)  STEP }
    { f32x4 i2 = b2q + G8;  SMALLT(8)  STEP }
    { f32x4 i2 = b2q + G9;  SMALLT(9)  STEP }
    { f32x4 i2 = b2q + G10; SMALLT(10) STEP }
    { f32x4 i2 = b2q + G11; SMALLT(11) STEP }
    { f32x4 i2 = b2q + G12; SMALLT(12) STEP }
    { f32x4 i2 = b2q + G13; SMALLT(13) STEP }
    { f32x4 i2 = b2q + G14; SMALLT(14) STEP }
    { f32x4 i2 = b2q + G15; SMALLT(15) STEP }

    const int my = c0 + c1 + c2 + c3;
    if (my) atomicAdd(&tot, my);
    __syncthreads();

    if (tot == 0) return;                    // out already = bout

    rrow[jc + 0] = (float)c0 / 15.0f;
    rrow[jc + 1] = (float)c1 / 15.0f;
    rrow[jc + 2] = (float)c2 / 15.0f;
    rrow[jc + 3] = (float)c3 / 15.0f;
    __syncthreads();
    if (tid < D_OUT) {
        float a = bout[tid];
        const float* wrow = Wout + (size_t)tid * H_SZ;
        for (int j = 0; j < H_SZ; ++j) a = fmaf(rrow[j], wrow[j], a);
        out[(size_t)b * D_OUT + tid] = a;
    }
}

// ---------------------------------------------------------------- launch
extern "C" void kernel_launch(void* const* d_in, const int* in_sizes, int n_in,
                              void* d_out, int out_size, void* d_ws, size_t ws_size,
                              hipStream_t stream) {
    const float* x    = (const float*)d_in[0];
    const float* W1   = (const float*)d_in[1];
    const float* b1   = (const float*)d_in[2];
    const float* W2   = (const float*)d_in[3];
    const float* b2   = (const float*)d_in[4];
    const float* Wout = (const float*)d_in[5];
    const float* bout = (const float*)d_in[6];
    float* out = (float*)d_out;

    char* ws = (char*)d_ws;
    unsigned short* W2cb   = (unsigned short*)(ws);                   // 2 MB + 2 KB pad
    float*          cert2d = (float*)(ws + (4 << 20));                // 8*8192*4 = 256 KB
    float*          mx     = (float*)(ws + (5 << 20));                // 4 KB
    float*          mxb2   = (float*)(ws + (5 << 20) + (4 << 10));    // 4 B
    unsigned char*  kbuf   = (unsigned char*)(ws + (8 << 20));        // 8 MB

    k0_transpose<<<dim3(H_SZ / 32, H_SZ / 32), dim3(32, 8), 0, stream>>>(W2, W2cb);
    k0_colmax<<<H_SZ / 256, 256, 0, stream>>>(W2, b2, mx, mxb2);
    k0_bcast<<<B_SZ * D_OUT / 4 / 256, 256, 0, stream>>>(bout, out);
    k1_mfma<<<dim3(B_SZ / 128, H_SZ / 128), 256, 0, stream>>>(x, W1, b1, mx, kbuf, cert2d);
    k2_final<<<B_SZ, 256, 0, stream>>>(kbuf, W2cb, b2, Wout, bout, cert2d, mxb2, out);
}

// Round 20
// 53.129 us; speedup vs baseline: 2.5327x; 2.5327x over previous
//
#include <hip/hip_runtime.h>
#include <hip/hip_bf16.h>

// SpikingPolicyNet: B=8192, D_in=256, H=1024, D_out=64, T=15, TAU=20, V_TH=1
//
// Pipeline (R20 = R19 with parallelized colmax):
//  K0  : W2 -> W2cb (bf16 W2^T + zero sentinel row; rare path only)
//  K0c1: partial column maxima pmx[chunk][j] over 32-row chunks (128 blocks,
//        coalesced, no atomics, no init)
//  K0c2: mx[j] = max_chunk pmx[chunk][j]; mxb2 = max_i relu(b2_i)
//  K0d : out[b][:] = bout (unconditional broadcast; k2 overwrites flagged rows)
//  K1  : bf16-MFMA x@W1.T; epilogue folds b1, computes closed-form spike
//        interval k = ceil(log2(1-1/I)/log2(0.95)) (spikes at t=k,2k,...),
//        writes byte-plane kb[b][j], reduces CTAB[k]*mx[j] per row into LDS,
//        writes block-partial to cert2d[colblock][row] (no atomics, no init).
//  K2  : certv = sum_cb cert2d[cb][b] + 0.5367*mxb2. Soundness:
//        v2_t(no-reset) >= v2_t; I2_s <= relu(b2_i) + sum_j relu(w_ij)[k_j|s]
//        => max v2 <= 0.5367*max relu(b2) + sum_j coef(k_j)*mx[j];
//        coef(k)=0.05*max_t sum_{m:mk<=t<=15} 0.95^(t-mk) (=0.05, k>=8);
//        CTAB[k]=coef(k-1) absorbs +-1 k-flips. certv<=0.98 (typ ~0.2,
//        ~25-sigma margin) proves zero s2 spikes (absmax==0 R1-R19 incl
//        full-fp32 R1). Flagged rows (expected 0) run the R16/R17-proven
//        exact 8-bucket G-register recurrence inline.

#define B_SZ   8192
#define D_IN   256
#define H_SZ   1024
#define D_OUT  64
#define T_STEPS 15
#define CERT_THR 0.98f

typedef __attribute__((ext_vector_type(8))) short short8;
typedef __attribute__((ext_vector_type(4))) float f32x4;

__device__ __constant__ float CTAB[16] = {   // CTAB[k] = coef(k-1), k-flip robust
    0.05f,     0.53670f, 0.53670f, 0.26271f, 0.18815f, 0.12390f, 0.11863f,
    0.086755f, 0.084882f, 0.05f,   0.05f,    0.05f,    0.05f,    0.05f,
    0.05f,     0.05f};

static __device__ __forceinline__ unsigned int pk_bf16(float lo, float hi) {
    return (__builtin_bit_cast(unsigned int, hi) & 0xffff0000u) |
           (__builtin_bit_cast(unsigned int, lo) >> 16);
}
static __device__ __forceinline__ f32x4 unp4(uint2 w) {
    f32x4 r;
    r.x = __builtin_bit_cast(float, w.x << 16);
    r.y = __builtin_bit_cast(float, w.x & 0xffff0000u);
    r.z = __builtin_bit_cast(float, w.y << 16);
    r.w = __builtin_bit_cast(float, w.y & 0xffff0000u);
    return r;
}

// ---------------------------------------------------------------- K0: transpose (+ sentinel row)
__global__ __launch_bounds__(256) void k0_transpose(const float* __restrict__ W2,
                                                    unsigned short* __restrict__ W2cb) {
    __shared__ float tile[32][33];
    const int bx = blockIdx.x * 32;
    const int by = blockIdx.y * 32;
    const int tx = threadIdx.x;
    const int ty = threadIdx.y;
    #pragma unroll
    for (int i = ty; i < 32; i += 8)
        tile[i][tx] = W2[(size_t)(by + i) * H_SZ + bx + tx];
    __syncthreads();
    #pragma unroll
    for (int i = ty; i < 32; i += 8)
        W2cb[(size_t)(bx + i) * H_SZ + by + tx] =
            (unsigned short)(__builtin_bit_cast(unsigned int, tile[tx][i]) >> 16);
    if (blockIdx.x == 0 && blockIdx.y == 0) {        // zero sentinel row 1024
        const int t = ty * 32 + tx;
        #pragma unroll
        for (int i = 0; i < 4; ++i)
            W2cb[(size_t)H_SZ * H_SZ + i * 256 + t] = 0;
    }
}

// ---------------------------------------------------------------- K0c1: partial column maxima
__global__ __launch_bounds__(256) void k0_colmax1(const float* __restrict__ W2,
                                                  float* __restrict__ pmx) {
    const int col = blockIdx.x * 256 + threadIdx.x;
    const int r0  = blockIdx.y * 32;
    float m = 0.f;                                   // relu: start at 0
    #pragma unroll
    for (int i = 0; i < 32; ++i)                     // coalesced row loads
        m = fmaxf(m, W2[(size_t)(r0 + i) * H_SZ + col]);
    pmx[(size_t)blockIdx.y * H_SZ + col] = m;
}

// ---------------------------------------------------------------- K0c2: reduce partials + b2 max
__global__ __launch_bounds__(256) void k0_colmax2(const float* __restrict__ pmx,
                                                  const float* __restrict__ b2,
                                                  float* __restrict__ mx,
                                                  float* __restrict__ mxb2) {
    const int col = blockIdx.x * 256 + threadIdx.x;
    float m = 0.f;
    #pragma unroll
    for (int i = 0; i < 32; ++i)
        m = fmaxf(m, pmx[(size_t)i * H_SZ + col]);
    mx[col] = m;

    if (blockIdx.x == 0) {                            // mxb2 = max relu(b2)
        __shared__ float red[256];
        const int tid = threadIdx.x;
        float m2 = 0.f;
        #pragma unroll
        for (int i = 0; i < 4; ++i) m2 = fmaxf(m2, b2[tid + 256 * i]);
        red[tid] = m2;
        __syncthreads();
        if (tid == 0) {
            float r = 0.f;
            for (int i = 0; i < 256; ++i) r = fmaxf(r, red[i]);
            *mxb2 = r;
        }
    }
}

// ---------------------------------------------------------------- K0d: out = bout broadcast
__global__ __launch_bounds__(256) void k0_bcast(const float* __restrict__ bout,
                                                float* __restrict__ out) {
    __shared__ float4 bq[16];
    const int tid = threadIdx.x;
    if (tid < 16) bq[tid] = *(const float4*)&bout[tid * 4];
    __syncthreads();
    const int idx = blockIdx.x * 256 + tid;           // float4 index
    *(float4*)&out[(size_t)idx * 4] = bq[idx & 15];
}

// ---------------------------------------------------------------- K1: MFMA + kb + LDS cert partials
__global__ __launch_bounds__(256) void k1_mfma(const float* __restrict__ A,
                                               const float* __restrict__ Bw,
                                               const float* __restrict__ b1,
                                               const float* __restrict__ mx,
                                               unsigned char* __restrict__ kb,
                                               float* __restrict__ cert2d) {
    __shared__ unsigned int As4[2048];   // 128 rows x 32 bf16, 16B-chunk XOR swizzle
    __shared__ unsigned int Bs4[2048];
    __shared__ float certs[128];
    const int tid  = threadIdx.x;
    const int m0   = blockIdx.x * 128;
    const int n0   = blockIdx.y * 128;
    const int lane = tid & 63;
    const int wid  = tid >> 6;
    const int wr   = wid >> 1, wc = wid & 1;

    const int row0 = tid >> 2;
    const int row1 = row0 + 64;
    const int q0   = tid & 3;

    f32x4 acc[4][4] = {};
    float4 s0[8], s1[8];

    auto LOAD = [&](float4* s, int kbk) {
        const float* pa0 = A  + (m0 + row0) * D_IN + kbk + q0 * 8;
        const float* pa1 = A  + (m0 + row1) * D_IN + kbk + q0 * 8;
        const float* pb0 = Bw + (n0 + row0) * D_IN + kbk + q0 * 8;
        const float* pb1 = Bw + (n0 + row1) * D_IN + kbk + q0 * 8;
        s[0] = *(const float4*)pa0; s[1] = *(const float4*)(pa0 + 4);
        s[2] = *(const float4*)pa1; s[3] = *(const float4*)(pa1 + 4);
        s[4] = *(const float4*)pb0; s[5] = *(const float4*)(pb0 + 4);
        s[6] = *(const float4*)pb1; s[7] = *(const float4*)(pb1 + 4);
    };
    auto WRITE = [&](const float4* s) {
        const int i0 = row0 * 16 + (q0 ^ ((row0 >> 1) & 3)) * 4;
        const int i1 = row1 * 16 + (q0 ^ ((row1 >> 1) & 3)) * 4;
        *(uint4*)&As4[i0] = make_uint4(pk_bf16(s[0].x, s[0].y), pk_bf16(s[0].z, s[0].w),
                                       pk_bf16(s[1].x, s[1].y), pk_bf16(s[1].z, s[1].w));
        *(uint4*)&As4[i1] = make_uint4(pk_bf16(s[2].x, s[2].y), pk_bf16(s[2].z, s[2].w),
                                       pk_bf16(s[3].x, s[3].y), pk_bf16(s[3].z, s[3].w));
        *(uint4*)&Bs4[i0] = make_uint4(pk_bf16(s[4].x, s[4].y), pk_bf16(s[4].z, s[4].w),
                                       pk_bf16(s[5].x, s[5].y), pk_bf16(s[5].z, s[5].w));
        *(uint4*)&Bs4[i1] = make_uint4(pk_bf16(s[6].x, s[6].y), pk_bf16(s[6].z, s[6].w),
                                       pk_bf16(s[7].x, s[7].y), pk_bf16(s[7].z, s[7].w));
    };
    auto COMPUTE = [&]() {
        short8 afr[4], bfr[4];
        const int q  = lane >> 4;
        const int lr = lane & 15;
        #pragma unroll
        for (int mf = 0; mf < 4; ++mf) {
            const int ra = wr * 64 + mf * 16 + lr;
            afr[mf] = *(const short8*)&As4[ra * 16 + (q ^ ((ra >> 1) & 3)) * 4];
            const int rb = wc * 64 + mf * 16 + lr;
            bfr[mf] = *(const short8*)&Bs4[rb * 16 + (q ^ ((rb >> 1) & 3)) * 4];
        }
        #pragma unroll
        for (int mf = 0; mf < 4; ++mf)
            #pragma unroll
            for (int nf = 0; nf < 4; ++nf)
                acc[mf][nf] = __builtin_amdgcn_mfma_f32_16x16x32_bf16(
                    afr[mf], bfr[nf], acc[mf][nf], 0, 0, 0);
    };

    LOAD(s0, 0);
    for (int kk = 0; kk < D_IN; kk += 64) {
        if (kk + 32 < D_IN) LOAD(s1, kk + 32);
        __syncthreads();
        WRITE(s0);
        __syncthreads();
        COMPUTE();
        if (kk + 64 < D_IN) LOAD(s0, kk + 64);
        __syncthreads();
        WRITE(s1);
        __syncthreads();
        COMPUTE();
    }

    __syncthreads();
    if (tid < 128) certs[tid] = 0.f;
    __syncthreads();

    // Epilogue: I = acc + b1[col]; k = ceil(log2(1-1/I)*-13.5134035), 0 = none.
    const int lr = lane & 15;
    const int qq = lane >> 4;
    float b1v[4];
    #pragma unroll
    for (int nf = 0; nf < 4; ++nf) b1v[nf] = b1[n0 + wc * 64 + nf * 16 + lr];

    #pragma unroll
    for (int mf = 0; mf < 4; ++mf) {
        const int rloc = wr * 64 + mf * 16 + qq * 4;     // row - m0
        #pragma unroll
        for (int nf = 0; nf < 4; ++nf) {
            const int c = n0 + wc * 64 + nf * 16 + lr;
            const float mxc = mx[c];
            #pragma unroll
            for (int r = 0; r < 4; ++r) {
                const float I = acc[mf][nf][r] + b1v[nf];
                int k = 0;
                if (I > 1.8632055f) {
                    const float l2 = __builtin_amdgcn_logf(1.0f - __builtin_amdgcn_rcpf(I));
                    int kc = (int)__builtin_ceilf(l2 * -13.5134035f);
                    k = kc < 1 ? 1 : (kc > 15 ? 15 : kc);
                    atomicAdd(&certs[rloc + r], CTAB[k] * mxc);   // LDS atomic
                }
                kb[(size_t)(m0 + rloc + r) * H_SZ + c] = (unsigned char)k;
            }
        }
    }
    __syncthreads();
    if (tid < 128)                                        // block-private slab, no atomics
        cert2d[(size_t)blockIdx.y * B_SZ + m0 + tid] = certs[tid];
}

// ---------------------------------------------------------------- K2: cert check (+ exact fallback)
#define BQ(IDX, GV)                                                           \
    { const uint2 eq = *(const uint2*)&ent[IDX];                              \
      const unsigned sa = (unsigned)__builtin_amdgcn_readfirstlane((int)eq.x);\
      const unsigned sb = (unsigned)__builtin_amdgcn_readfirstlane((int)eq.y);\
      const uint2 qa = *(const uint2*)(W2cb + ((size_t)(sa & 0xffffu) << 10) + jc); \
      const uint2 qb = *(const uint2*)(W2cb + ((size_t)(sa >> 16) << 10) + jc);     \
      const uint2 qc = *(const uint2*)(W2cb + ((size_t)(sb & 0xffffu) << 10) + jc); \
      const uint2 qd = *(const uint2*)(W2cb + ((size_t)(sb >> 16) << 10) + jc);     \
      GV += unp4(qa); GV += unp4(qb); GV += unp4(qc); GV += unp4(qd); }

#define BLOOP(GV, R)                                                          \
    for (int i = stt[R]; i < stt[(R) + 1]; i += 4) BQ(i, GV)

__host__ __device__ constexpr unsigned divmask(int t) {   // bit k set iff k | t
    unsigned m = 0;
    for (int k = 1; k <= 15; ++k) if (t % k == 0) m |= 1u << k;
    return m;
}

#define SMALLT(T)                                                             \
    { constexpr unsigned dm = divmask(T);                                     \
      for (int i = 0; i < nsm; ++i) {                                         \
          const int ee = __builtin_amdgcn_readfirstlane((int)ent[i]);         \
          if ((dm >> (ee >> 12)) & 1) {                                       \
              const uint2 w = *(const uint2*)(W2cb + ((size_t)(ee & 0xfffu) << 10) + jc); \
              i2 += unp4(w); } } }

#define STEP                                                                  \
    { v2 = v2 * 0.95f + i2 * 0.05f;                                           \
      if (v2.x > 1.0f) { v2.x = 0.f; ++c0; }                                  \
      if (v2.y > 1.0f) { v2.y = 0.f; ++c1; }                                  \
      if (v2.z > 1.0f) { v2.z = 0.f; ++c2; }                                  \
      if (v2.w > 1.0f) { v2.w = 0.f; ++c3; } }

__global__ __launch_bounds__(256) void k2_final(const unsigned char* __restrict__ kb,
                                                const unsigned short* __restrict__ W2cb,
                                                const float* __restrict__ b2,
                                                const float* __restrict__ Wout,
                                                const float* __restrict__ bout,
                                                const float* __restrict__ cert2d,
                                                const float* __restrict__ mxb2,
                                                float* __restrict__ out) {
    const int b   = blockIdx.x;
    const int tid = threadIdx.x;
    const int jc  = tid * 4;

    float certv = 0.536708f * (*mxb2);
    #pragma unroll
    for (int cb = 0; cb < 8; ++cb) certv += cert2d[(size_t)cb * B_SZ + b];

    if (certv <= CERT_THR) return;           // ~always: out already = bout (K0d)

    // ---- exact path (R16/R17-proven): 8-bucket G-register recurrence
    __shared__ int cnt[16];
    __shared__ int curs[16];
    __shared__ int stb[9];
    __shared__ int tot;
    __shared__ __align__(8) unsigned short ent[1064];
    __shared__ float rrow[H_SZ];

    if (tid < 16) { cnt[tid] = 0; if (tid == 0) tot = 0; }
    const unsigned int kw = *(const unsigned int*)(kb + (size_t)b * H_SZ + jc);
    const f32x4 b2q = *(const f32x4*)&b2[jc];
    __syncthreads();

    if (kw) {
        #pragma unroll
        for (int u = 0; u < 4; ++u) {
            const unsigned int ku = (kw >> (8 * u)) & 0xffu;
            if (ku) atomicAdd(&cnt[(ku >= 8) ? (int)ku : 0], 1);
        }
    }
    __syncthreads();
    if (tid < 9) {
        int s = (cnt[0] + 3) & ~3;
        for (int r = 0; r < tid; ++r) s += (cnt[8 + r] + 3) & ~3;
        stb[tid] = s;
        if (tid < 8) curs[8 + tid] = s;
        if (tid == 0) curs[0] = 0;
    }
    __syncthreads();
    if (kw) {
        #pragma unroll
        for (int u = 0; u < 4; ++u) {
            const unsigned int ku = (kw >> (8 * u)) & 0xffu;
            if (ku) {
                if (ku >= 8) {
                    const int p = atomicAdd(&curs[ku], 1);
                    ent[p] = (unsigned short)(jc + u);
                } else {
                    const int p = atomicAdd(&curs[0], 1);
                    ent[p] = (unsigned short)((jc + u) | (ku << 12));
                }
            }
        }
    }
    if (tid < 8) {
        for (int p = stb[tid] + cnt[8 + tid]; p < stb[tid + 1]; ++p)
            ent[p] = (unsigned short)H_SZ;
    }
    __syncthreads();

    int stt[9];
    #pragma unroll
    for (int r = 0; r < 9; ++r) stt[r] = __builtin_amdgcn_readfirstlane(stb[r]);
    const int nsm = __builtin_amdgcn_readfirstlane(cnt[0]);

    f32x4 G8 = {0,0,0,0}, G9 = {0,0,0,0}, G10 = {0,0,0,0}, G11 = {0,0,0,0};
    f32x4 G12 = {0,0,0,0}, G13 = {0,0,0,0}, G14 = {0,0,0,0}, G15 = {0,0,0,0};
    BLOOP(G8, 0)  BLOOP(G9, 1)  BLOOP(G10, 2) BLOOP(G11, 3)
    BLOOP(G12, 4) BLOOP(G13, 5) BLOOP(G14, 6) BLOOP(G15, 7)

    f32x4 v2 = {0,0,0,0};
    int c0 = 0, c1 = 0, c2 = 0, c3 = 0;
    { f32x4 i2 = b2q;       SMALLT(1)  STEP }
    { f32x4 i2 = b2q;       SMALLT(2)  STEP }
    { f32x4 i2 = b2q;       SMALLT(3)  STEP }
    { f32x4 i2 = b2q;       SMALLT(4)  STEP }
    { f32x4 i2 = b2q;       SMALLT(5)  STEP }
    { f32x4 i2 = b2q;       SMALLT(6)  STEP }
    { f32x4 i2 = b2q;       SMALLT(7)  STEP }
    { f32x4 i2 = b2q + G8;  SMALLT(8)  STEP }
    { f32x4 i2 = b2q + G9;  SMALLT(9)  STEP }
    { f32x4 i2 = b2q + G10; SMALLT(10) STEP }
    { f32x4 i2 = b2q + G11; SMALLT(11) STEP }
    { f32x4 i2 = b2q + G12; SMALLT(12) STEP }
    { f32x4 i2 = b2q + G13; SMALLT(13) STEP }
    { f32x4 i2 = b2q + G14; SMALLT(14) STEP }
    { f32x4 i2 = b2q + G15; SMALLT(15) STEP }

    const int my = c0 + c1 + c2 + c3;
    if (my) atomicAdd(&tot, my);
    __syncthreads();

    if (tot == 0) return;                    // out already = bout

    rrow[jc + 0] = (float)c0 / 15.0f;
    rrow[jc + 1] = (float)c1 / 15.0f;
    rrow[jc + 2] = (float)c2 / 15.0f;
    rrow[jc + 3] = (float)c3 / 15.0f;
    __syncthreads();
    if (tid < D_OUT) {
        float a = bout[tid];
        const float* wrow = Wout + (size_t)tid * H_SZ;
        for (int j = 0; j < H_SZ; ++j) a = fmaf(rrow[j], wrow[j], a);
        out[(size_t)b * D_OUT + tid] = a;
    }
}

// ---------------------------------------------------------------- launch
extern "C" void kernel_launch(void* const* d_in, const int* in_sizes, int n_in,
                              void* d_out, int out_size, void* d_ws, size_t ws_size,
                              hipStream_t stream) {
    const float* x    = (const float*)d_in[0];
    const float* W1   = (const float*)d_in[1];
    const float* b1   = (const float*)d_in[2];
    const float* W2   = (const float*)d_in[3];
    const float* b2   = (const float*)d_in[4];
    const float* Wout = (const float*)d_in[5];
    const float* bout = (const float*)d_in[6];
    float* out = (float*)d_out;

    char* ws = (char*)d_ws;
    unsigned short* W2cb   = (unsigned short*)(ws);                   // 2 MB + 2 KB pad
    float*          cert2d = (float*)(ws + (4 << 20));                // 256 KB
    float*          mx     = (float*)(ws + (5 << 20));                // 4 KB
    float*          mxb2   = (float*)(ws + (5 << 20) + (4 << 10));    // 4 B
    float*          pmx    = (float*)(ws + (5 << 20) + (8 << 10));    // 128 KB
    unsigned char*  kbuf   = (unsigned char*)(ws + (8 << 20));        // 8 MB

    k0_transpose<<<dim3(H_SZ / 32, H_SZ / 32), dim3(32, 8), 0, stream>>>(W2, W2cb);
    k0_colmax1<<<dim3(H_SZ / 256, 32), 256, 0, stream>>>(W2, pmx);
    k0_colmax2<<<H_SZ / 256, 256, 0, stream>>>(pmx, b2, mx, mxb2);
    k0_bcast<<<B_SZ * D_OUT / 4 / 256, 256, 0, stream>>>(bout, out);
    k1_mfma<<<dim3(B_SZ / 128, H_SZ / 128), 256, 0, stream>>>(x, W1, b1, mx, kbuf, cert2d);
    k2_final<<<B_SZ, 256, 0, stream>>>(kbuf, W2cb, b2, Wout, bout, cert2d, mxb2, out);
}